// Round 9
// baseline (1018.657 us; speedup 1.0000x reference)
//
#include <hip/hip_runtime.h>
#include <hip/hip_bf16.h>

#define NN 100000
#define NROWS 100032      // NN rounded up to 64; rows >= NN are zero (gather sentinel)
#define NE 1600000
#define DD 128
#define NBUK 196          // ceil(100000 / 512) buckets of 512 target nodes
#define F1_BLOCKS 256
#define F3_BLOCKS 256

typedef unsigned short ushort_t;
typedef unsigned int uint_t;
typedef unsigned long long uint64_t_;
typedef __attribute__((ext_vector_type(8))) short bf16x8;
typedef __attribute__((ext_vector_type(4))) float f32x4;

__device__ __forceinline__ ushort_t bf16rne(float f) {
    uint_t u = __float_as_uint(f);
    u += 0x7FFF + ((u >> 16) & 1);
    return (ushort_t)(u >> 16);
}
__device__ __forceinline__ float bfLo(uint_t u) { return __uint_as_float(u << 16); }
__device__ __forceinline__ float bfHi(uint_t u) { return __uint_as_float(u & 0xFFFF0000u); }

// ---------------- CSR build (bucketed counting sort) ----------------

__global__ __launch_bounds__(256) void f1_bucket_count(const int* __restrict__ col,
                                                       int* __restrict__ bukCount) {
    __shared__ int hist[NBUK];
    for (int t = threadIdx.x; t < NBUK; t += 256) hist[t] = 0;
    __syncthreads();
    const int epb = (NE + F1_BLOCKS - 1) / F1_BLOCKS;
    const int e0 = blockIdx.x * epb;
    const int e1 = min(e0 + epb, NE);
    for (int e = e0 + threadIdx.x; e < e1; e += 256)
        atomicAdd(&hist[col[e] >> 9], 1);
    __syncthreads();
    for (int t = threadIdx.x; t < NBUK; t += 256)
        if (hist[t]) atomicAdd(&bukCount[t], hist[t]);
}

__global__ void f2_bucket_scan(const int* __restrict__ bukCount,
                               int* __restrict__ bukBase,
                               int* __restrict__ bukCursor,
                               int* __restrict__ offsets) {
    __shared__ int s[256];
    const int t = threadIdx.x;
    int v = (t < NBUK) ? bukCount[t] : 0;
    s[t] = v;
    __syncthreads();
    for (int off = 1; off < 256; off <<= 1) {
        int tmp = (t >= off) ? s[t - off] : 0;
        __syncthreads();
        s[t] += tmp;
        __syncthreads();
    }
    int excl = s[t] - v;
    if (t < NBUK) { bukBase[t] = excl; bukCursor[t] = excl; }
    if (t == 255) { bukBase[NBUK] = s[255]; offsets[NN] = s[255]; }
}

// per-wave LDS histograms; ebuf packed as (row<<9)|col_local
__global__ __launch_bounds__(256) void f3_scatter(const int* __restrict__ row,
                                                  const int* __restrict__ col,
                                                  int* __restrict__ bukCursor,
                                                  int* __restrict__ ebuf) {
    __shared__ int hist[4][NBUK];
    __shared__ int base[4][NBUK];
    const int t = threadIdx.x;
    const int w = t >> 6;
    const int lane = t & 63;
    for (int i = t; i < 4 * NBUK; i += 256) (&hist[0][0])[i] = 0;
    __syncthreads();
    const int epb = (NE + F3_BLOCKS - 1) / F3_BLOCKS;
    const int e0 = blockIdx.x * epb;
    const int e1 = min(e0 + epb, NE);
    const int wepb = (e1 - e0 + 3) >> 2;
    const int we0 = e0 + w * wepb;
    const int we1 = min(we0 + wepb, e1);
    for (int e = we0 + lane; e < we1; e += 64)
        atomicAdd(&hist[w][col[e] >> 9], 1);
    __syncthreads();
    if (t < NBUK) {
        int h0 = hist[0][t], h1 = hist[1][t], h2 = hist[2][t], h3 = hist[3][t];
        int tot = h0 + h1 + h2 + h3;
        int g = tot ? atomicAdd(&bukCursor[t], tot) : 0;
        base[0][t] = g; base[1][t] = g + h0;
        base[2][t] = g + h0 + h1; base[3][t] = g + h0 + h1 + h2;
        hist[0][t] = 0; hist[1][t] = 0; hist[2][t] = 0; hist[3][t] = 0;
    }
    __syncthreads();
    for (int e = we0 + lane; e < we1; e += 64) {
        int c = col[e];
        int b = c >> 9;
        int r = atomicAdd(&hist[w][b], 1);
        ebuf[base[w][b] + r] = (row[e] << 9) | (c & 511);
    }
}

__global__ __launch_bounds__(256) void f4_finalize(const int* __restrict__ ebuf,
                                                   const int* __restrict__ bukBase,
                                                   int* __restrict__ offsets,
                                                   float* __restrict__ dis,
                                                   int* __restrict__ csr_src) {
    __shared__ int cnt[512];
    __shared__ int cur[512];
    __shared__ int s[256];
    const int t = threadIdx.x;
    const int colBase = blockIdx.x << 9;
    const int ncols = min(512, NN - colBase);
    cnt[t] = 0; cnt[t + 256] = 0;
    __syncthreads();
    const int eb0 = bukBase[blockIdx.x];
    const int eb1 = bukBase[blockIdx.x + 1];
    for (int e = eb0 + t; e < eb1; e += 256)
        atomicAdd(&cnt[ebuf[e] & 511], 1);
    __syncthreads();
    const int c0 = cnt[2 * t], c1 = cnt[2 * t + 1];
    const int psum = c0 + c1;
    s[t] = psum;
    __syncthreads();
    for (int off = 1; off < 256; off <<= 1) {
        int tmp = (t >= off) ? s[t - off] : 0;
        __syncthreads();
        s[t] += tmp;
        __syncthreads();
    }
    const int exclPair = s[t] - psum;
    const int g0 = eb0 + exclPair;
    const int g1 = g0 + c0;
    cur[2 * t] = g0; cur[2 * t + 1] = g1;
    if (2 * t < ncols)     { offsets[colBase + 2 * t]     = g0; dis[colBase + 2 * t]     = rsqrtf((float)(c0 + 1)); }
    if (2 * t + 1 < ncols) { offsets[colBase + 2 * t + 1] = g1; dis[colBase + 2 * t + 1] = rsqrtf((float)(c1 + 1)); }
    __syncthreads();
    for (int e = eb0 + t; e < eb1; e += 256) {
        int pc = ebuf[e];
        int p = atomicAdd(&cur[pc & 511], 1);
        csr_src[p] = pc >> 9;
    }
}

// ---------------- W prep: bf16 + transpose wT[l][col][k] ----------------

__global__ __launch_bounds__(256) void wt_kernel(const float* __restrict__ Ws,
                                                 ushort_t* __restrict__ wT) {
    int idx = blockIdx.x * 256 + threadIdx.x;
    if (idx >= 3 * 128 * 16) return;
    int l = idx >> 11;
    int r = idx & 2047;
    int c = r >> 4;
    int kc = r & 15;
    const float* w = Ws + l * 16384;
    ushort_t tmp[8];
#pragma unroll
    for (int e = 0; e < 8; ++e)
        tmp[e] = bf16rne(w[(kc * 8 + e) * 128 + c]);
    *(uint4*)&wT[(size_t)l * 16384 + c * 128 + kc * 8] = *(uint4*)tmp;
}

// ---------------- MFMA GEMM -> plane-major Y ----------------
// Y layout: 8 planes, plane s = [NROWS][8 uints] = dims [s*16, s*16+16) of each row.
// Rows >= NN written as zero in every plane (gather sentinels).

template<bool XF32>
__global__ __launch_bounds__(256) void gemm_mfma(const void* __restrict__ Xv,
                                                 const ushort_t* __restrict__ wT,
                                                 const float* __restrict__ dis,
                                                 ushort_t* __restrict__ Y) {
    __shared__ short smem[128 * 136];   // 34.8 KB: W-stage, then bf16-C stage
    {
        const uint4* src = (const uint4*)wT;
        int t = threadIdx.x;
#pragma unroll
        for (int i = 0; i < 8; ++i) {
            int idx = i * 256 + t;
            int rowc = idx >> 4;
            int kc = idx & 15;
            uint4 v = src[idx];
            *(uint4*)&smem[rowc * 136 + kc * 8] = v;
        }
    }
    __syncthreads();

    const int wave = threadIdx.x >> 6;
    const int lane = threadIdx.x & 63;
    const int m = lane & 15;
    const int kg = lane >> 4;
    const int r0 = blockIdx.x * 64 + wave * 16;
    const int rowA = min(r0 + m, NN - 1);

    f32x4 acc[8];
#pragma unroll
    for (int ct = 0; ct < 8; ++ct) acc[ct] = (f32x4){0.f, 0.f, 0.f, 0.f};

#pragma unroll
    for (int ks = 0; ks < 4; ++ks) {
        bf16x8 af;
        if (XF32) {
            const float* xp = (const float*)Xv + (size_t)rowA * DD + ks * 32 + kg * 8;
            float4 f0 = *(const float4*)xp;
            float4 f1 = *(const float4*)(xp + 4);
            af[0] = (short)bf16rne(f0.x); af[1] = (short)bf16rne(f0.y);
            af[2] = (short)bf16rne(f0.z); af[3] = (short)bf16rne(f0.w);
            af[4] = (short)bf16rne(f1.x); af[5] = (short)bf16rne(f1.y);
            af[6] = (short)bf16rne(f1.z); af[7] = (short)bf16rne(f1.w);
        } else {
            const ushort_t* xp = (const ushort_t*)Xv + (size_t)rowA * DD + ks * 32 + kg * 8;
            af = *(const bf16x8*)xp;
        }
#pragma unroll
        for (int ct = 0; ct < 8; ++ct) {
            bf16x8 bf = *(const bf16x8*)&smem[(ct * 16 + m) * 136 + ks * 32 + kg * 8];
            acc[ct] = __builtin_amdgcn_mfma_f32_16x16x32_bf16(af, bf, acc[ct], 0, 0, 0);
        }
    }

    __syncthreads();   // all waves done reading W; smem becomes C-stage

    // C/D: col = ct*16 + m, row = kg*4 + rg  [m89-verified]
    ushort_t* sl = (ushort_t*)smem;          // [64 rows][132 cols]
    const int rbase = r0 + kg * 4;
    float dv[4];
#pragma unroll
    for (int rg = 0; rg < 4; ++rg) dv[rg] = dis[min(rbase + rg, NN - 1)];
#pragma unroll
    for (int ct = 0; ct < 8; ++ct) {
#pragma unroll
        for (int rg = 0; rg < 4; ++rg)
            sl[(wave * 16 + kg * 4 + rg) * 132 + ct * 16 + m] = bf16rne(acc[ct][rg] * dv[rg]);
    }

    // readback (within-wave rows: i>>4 == threadIdx.x>>6) and plane-major store
    const int i = threadIdx.x >> 2;          // row within block tile 0..63
    const int q = threadIdx.x & 3;           // 8B chunk within 32B slice
    const int grow = blockIdx.x * 64 + i;
    const bool ok = grow < NN;
    const ushort_t* rb = sl + i * 132;
    uint64_t_* lp2 = (uint64_t_*)Y;
#pragma unroll
    for (int s = 0; s < 8; ++s) {
        const uint_t* p = (const uint_t*)(rb + s * 16 + q * 4);
        uint64_t_ d = (uint64_t_)p[0] | ((uint64_t_)p[1] << 32);
        uint64_t_ z = ok ? d : 0ull;
        __builtin_nontemporal_store(z, &lp2[((size_t)s * NROWS + grow) * 4 + q]);
    }
}

// ---------------- aggregation (plane-sliced, L2-resident gather) ----------------
// Block = 4 waves = 4 nodes, all on slice s = bid&7 (-> XCD s by round-robin).
// Wave = 1 node x 8 edge-slots x 8 lanes (32B per edge). Self folded as edge j==deg.

template<bool F32OUT>
__global__ __launch_bounds__(256) void agg_kernel(const uint_t* __restrict__ lin_planes,
                                                  const int* __restrict__ offsets,
                                                  const int* __restrict__ csr_src,
                                                  const float* __restrict__ dis,
                                                  const float* __restrict__ bias,
                                                  void* __restrict__ outv) {
    const int bid = blockIdx.x;                 // 200000 blocks
    const int s   = bid & 7;                    // slice == XCD (heuristic)
    const int g   = bid >> 3;                   // node group [0, 25000)
    const int w    = threadIdx.x >> 6;
    const int lane = threadIdx.x & 63;
    const int es   = lane >> 3;                 // edge slot 0..7
    const int u    = lane & 7;                  // uint within 32B slice
    const int v = g * 4 + w;

    const int start = offsets[v];
    const int deg   = offsets[v + 1] - start;

    const uint_t* plane = lin_planes + (size_t)s * (NROWS * 8);

    float accx = 0.f, accy = 0.f;
    for (int k = 0; k <= deg; k += 8) {         // <= : slot j==deg is the self-loop
        int j = k + es;
        int cj = j < deg ? j : 0;
        int src = __builtin_nontemporal_load(&csr_src[start + cj]);
        src = j < deg ? src : (j == deg ? v : NN);   // NN = zero sentinel row
        uint_t a = plane[((uint_t)src << 3) + u];
        accx += bfLo(a); accy += bfHi(a);
    }
    accx += __shfl_xor(accx, 8);  accy += __shfl_xor(accy, 8);
    accx += __shfl_xor(accx, 16); accy += __shfl_xor(accy, 16);
    accx += __shfl_xor(accx, 32); accy += __shfl_xor(accy, 32);

    const float dv = dis[v];
    const float2 b = ((const float2*)bias)[s * 8 + u];
    float rx = fmaxf(fmaf(dv, accx, b.x), 0.f);
    float ry = fmaxf(fmaf(dv, accy, b.y), 0.f);
    if (es == 0) {
        const size_t oidx = (size_t)v * 64 + s * 8 + u;
        if (F32OUT) {
            float2 o = make_float2(rx, ry);
            __builtin_nontemporal_store(*(const uint64_t_*)&o, (uint64_t_*)((float2*)outv + oidx));
        } else {
            uint_t pk = (uint_t)bf16rne(rx) | ((uint_t)bf16rne(ry) << 16);
            __builtin_nontemporal_store(pk, (uint_t*)outv + oidx);
        }
    }
}

// ---------------- launch ----------------

extern "C" void kernel_launch(void* const* d_in, const int* in_sizes, int n_in,
                              void* d_out, int out_size, void* d_ws, size_t ws_size,
                              hipStream_t stream) {
    const float* x   = (const float*)d_in[0];
    const int*   ei  = (const int*)d_in[1];
    const float* Ws  = (const float*)d_in[2];
    const float* bs  = (const float*)d_in[3];

    const int* row = ei;
    const int* col = ei + NE;

    char* ws = (char*)d_ws;
    // lin planes: 8 * NROWS * 32B = 25,608,192 B (ebuf aliases low part)
    ushort_t* lin    = (ushort_t*)(ws + 0);
    int*   ebuf      = (int*)  (ws + 0);          // 6,400,000 B packed (dead before gemm)
    ushort_t* hb     = (ushort_t*)(ws + 25608192);// 25,600,000 B bf16 inter-layer h (row-major)
    float* dis       = (float*)(ws + 51208192);   // 400,000 B
    int*   offsets   = (int*)  (ws + 51608192);   // 400,004 B
    int*   csr_src   = (int*)  (ws + 52008208);   // 6,400,000 B
    int*   bukCount  = (int*)  (ws + 58408208);   // 784 B
    int*   bukBase   = (int*)  (ws + 58409008);   // 788 B
    int*   bukCursor = (int*)  (ws + 58409808);   // 784 B
    ushort_t* wT     = (ushort_t*)(ws + 58410608);// 98,304 B

    (void)hipMemsetAsync(bukCount, 0, NBUK * sizeof(int), stream);
    f1_bucket_count<<<F1_BLOCKS, 256, 0, stream>>>(col, bukCount);
    f2_bucket_scan<<<1, 256, 0, stream>>>(bukCount, bukBase, bukCursor, offsets);
    f3_scatter<<<F3_BLOCKS, 256, 0, stream>>>(row, col, bukCursor, ebuf);
    f4_finalize<<<NBUK, 256, 0, stream>>>(ebuf, bukBase, offsets, dis, csr_src);
    wt_kernel<<<24, 256, 0, stream>>>(Ws, wT);

    const int gemmGrid = NROWS / 64;    // 1563
    const int aggGrid = (NN / 4) * 8;   // 200000
    // layer 0: f32 x -> lin planes ; agg -> bf16 hb (row-major)
    gemm_mfma<true><<<gemmGrid, 256, 0, stream>>>(x, wT, dis, lin);
    agg_kernel<false><<<aggGrid, 256, 0, stream>>>((const uint_t*)lin, offsets, csr_src, dis, bs, hb);
    // layer 1
    gemm_mfma<false><<<gemmGrid, 256, 0, stream>>>(hb, wT + 16384, dis, lin);
    agg_kernel<false><<<aggGrid, 256, 0, stream>>>((const uint_t*)lin, offsets, csr_src, dis, bs + DD, hb);
    // layer 2 -> f32 d_out
    gemm_mfma<false><<<gemmGrid, 256, 0, stream>>>(hb, wT + 32768, dis, lin);
    agg_kernel<true><<<aggGrid, 256, 0, stream>>>((const uint_t*)lin, offsets, csr_src, dis, bs + 2 * DD, d_out);
}

// Round 10
// 324.453 us; speedup vs baseline: 3.1396x; 3.1396x over previous
//
#include <hip/hip_runtime.h>
#include <hip/hip_bf16.h>

#define NN 100000
#define NROWS 100032      // NN rounded up to 64; rows >= NN are zero (gather sentinel)
#define NE 1600000
#define DD 128
#define NBUK 196          // ceil(100000 / 512) buckets of 512 target nodes
#define F1_BLOCKS 256
#define F3_BLOCKS 256

typedef unsigned short ushort_t;
typedef unsigned int uint_t;
typedef unsigned long long uint64_t_;
typedef __attribute__((ext_vector_type(8))) short bf16x8;
typedef __attribute__((ext_vector_type(4))) float f32x4;

__device__ __forceinline__ ushort_t bf16rne(float f) {
    uint_t u = __float_as_uint(f);
    u += 0x7FFF + ((u >> 16) & 1);
    return (ushort_t)(u >> 16);
}
__device__ __forceinline__ float bfLo(uint_t u) { return __uint_as_float(u << 16); }
__device__ __forceinline__ float bfHi(uint_t u) { return __uint_as_float(u & 0xFFFF0000u); }

// ---------------- CSR build (bucketed counting sort) ----------------

__global__ __launch_bounds__(256) void f1_bucket_count(const int* __restrict__ col,
                                                       int* __restrict__ bukCount) {
    __shared__ int hist[NBUK];
    for (int t = threadIdx.x; t < NBUK; t += 256) hist[t] = 0;
    __syncthreads();
    const int epb = (NE + F1_BLOCKS - 1) / F1_BLOCKS;
    const int e0 = blockIdx.x * epb;
    const int e1 = min(e0 + epb, NE);
    for (int e = e0 + threadIdx.x; e < e1; e += 256)
        atomicAdd(&hist[col[e] >> 9], 1);
    __syncthreads();
    for (int t = threadIdx.x; t < NBUK; t += 256)
        if (hist[t]) atomicAdd(&bukCount[t], hist[t]);
}

__global__ void f2_bucket_scan(const int* __restrict__ bukCount,
                               int* __restrict__ bukBase,
                               int* __restrict__ bukCursor,
                               int* __restrict__ offsets) {
    __shared__ int s[256];
    const int t = threadIdx.x;
    int v = (t < NBUK) ? bukCount[t] : 0;
    s[t] = v;
    __syncthreads();
    for (int off = 1; off < 256; off <<= 1) {
        int tmp = (t >= off) ? s[t - off] : 0;
        __syncthreads();
        s[t] += tmp;
        __syncthreads();
    }
    int excl = s[t] - v;
    if (t < NBUK) { bukBase[t] = excl; bukCursor[t] = excl; }
    if (t == 255) { bukBase[NBUK] = s[255]; offsets[NN] = s[255]; }
}

// per-wave LDS histograms; ebuf packed as (row<<9)|col_local
__global__ __launch_bounds__(256) void f3_scatter(const int* __restrict__ row,
                                                  const int* __restrict__ col,
                                                  int* __restrict__ bukCursor,
                                                  int* __restrict__ ebuf) {
    __shared__ int hist[4][NBUK];
    __shared__ int base[4][NBUK];
    const int t = threadIdx.x;
    const int w = t >> 6;
    const int lane = t & 63;
    for (int i = t; i < 4 * NBUK; i += 256) (&hist[0][0])[i] = 0;
    __syncthreads();
    const int epb = (NE + F3_BLOCKS - 1) / F3_BLOCKS;
    const int e0 = blockIdx.x * epb;
    const int e1 = min(e0 + epb, NE);
    const int wepb = (e1 - e0 + 3) >> 2;
    const int we0 = e0 + w * wepb;
    const int we1 = min(we0 + wepb, e1);
    for (int e = we0 + lane; e < we1; e += 64)
        atomicAdd(&hist[w][col[e] >> 9], 1);
    __syncthreads();
    if (t < NBUK) {
        int h0 = hist[0][t], h1 = hist[1][t], h2 = hist[2][t], h3 = hist[3][t];
        int tot = h0 + h1 + h2 + h3;
        int g = tot ? atomicAdd(&bukCursor[t], tot) : 0;
        base[0][t] = g; base[1][t] = g + h0;
        base[2][t] = g + h0 + h1; base[3][t] = g + h0 + h1 + h2;
        hist[0][t] = 0; hist[1][t] = 0; hist[2][t] = 0; hist[3][t] = 0;
    }
    __syncthreads();
    for (int e = we0 + lane; e < we1; e += 64) {
        int c = col[e];
        int b = c >> 9;
        int r = atomicAdd(&hist[w][b], 1);
        ebuf[base[w][b] + r] = (row[e] << 9) | (c & 511);
    }
}

__global__ __launch_bounds__(256) void f4_finalize(const int* __restrict__ ebuf,
                                                   const int* __restrict__ bukBase,
                                                   int* __restrict__ offsets,
                                                   float* __restrict__ dis,
                                                   int* __restrict__ csr_src) {
    __shared__ int cnt[512];
    __shared__ int cur[512];
    __shared__ int s[256];
    const int t = threadIdx.x;
    const int colBase = blockIdx.x << 9;
    const int ncols = min(512, NN - colBase);
    cnt[t] = 0; cnt[t + 256] = 0;
    __syncthreads();
    const int eb0 = bukBase[blockIdx.x];
    const int eb1 = bukBase[blockIdx.x + 1];
    for (int e = eb0 + t; e < eb1; e += 256)
        atomicAdd(&cnt[ebuf[e] & 511], 1);
    __syncthreads();
    const int c0 = cnt[2 * t], c1 = cnt[2 * t + 1];
    const int psum = c0 + c1;
    s[t] = psum;
    __syncthreads();
    for (int off = 1; off < 256; off <<= 1) {
        int tmp = (t >= off) ? s[t - off] : 0;
        __syncthreads();
        s[t] += tmp;
        __syncthreads();
    }
    const int exclPair = s[t] - psum;
    const int g0 = eb0 + exclPair;
    const int g1 = g0 + c0;
    cur[2 * t] = g0; cur[2 * t + 1] = g1;
    if (2 * t < ncols)     { offsets[colBase + 2 * t]     = g0; dis[colBase + 2 * t]     = rsqrtf((float)(c0 + 1)); }
    if (2 * t + 1 < ncols) { offsets[colBase + 2 * t + 1] = g1; dis[colBase + 2 * t + 1] = rsqrtf((float)(c1 + 1)); }
    __syncthreads();
    for (int e = eb0 + t; e < eb1; e += 256) {
        int pc = ebuf[e];
        int p = atomicAdd(&cur[pc & 511], 1);
        csr_src[p] = pc >> 9;
    }
}

// ---------------- W prep: bf16 + transpose wT[l][col][k] ----------------

__global__ __launch_bounds__(256) void wt_kernel(const float* __restrict__ Ws,
                                                 ushort_t* __restrict__ wT) {
    int idx = blockIdx.x * 256 + threadIdx.x;
    if (idx >= 3 * 128 * 16) return;
    int l = idx >> 11;
    int r = idx & 2047;
    int c = r >> 4;
    int kc = r & 15;
    const float* w = Ws + l * 16384;
    ushort_t tmp[8];
#pragma unroll
    for (int e = 0; e < 8; ++e)
        tmp[e] = bf16rne(w[(kc * 8 + e) * 128 + c]);
    *(uint4*)&wT[(size_t)l * 16384 + c * 128 + kc * 8] = *(uint4*)tmp;
}

// ---------------- MFMA GEMM -> plane-major Y ----------------
// Y layout: 8 planes, plane s = [NROWS][8 uints] = dims [s*16, s*16+16) of each row.
// Rows >= NN written as zero in every plane (gather sentinels).

template<bool XF32>
__global__ __launch_bounds__(256) void gemm_mfma(const void* __restrict__ Xv,
                                                 const ushort_t* __restrict__ wT,
                                                 const float* __restrict__ dis,
                                                 ushort_t* __restrict__ Y) {
    __shared__ short smem[128 * 136];   // 34.8 KB: W-stage, then bf16-C stage
    {
        const uint4* src = (const uint4*)wT;
        int t = threadIdx.x;
#pragma unroll
        for (int i = 0; i < 8; ++i) {
            int idx = i * 256 + t;
            int rowc = idx >> 4;
            int kc = idx & 15;
            uint4 v = src[idx];
            *(uint4*)&smem[rowc * 136 + kc * 8] = v;
        }
    }
    __syncthreads();

    const int wave = threadIdx.x >> 6;
    const int lane = threadIdx.x & 63;
    const int m = lane & 15;
    const int kg = lane >> 4;
    const int r0 = blockIdx.x * 64 + wave * 16;
    const int rowA = min(r0 + m, NN - 1);

    f32x4 acc[8];
#pragma unroll
    for (int ct = 0; ct < 8; ++ct) acc[ct] = (f32x4){0.f, 0.f, 0.f, 0.f};

#pragma unroll
    for (int ks = 0; ks < 4; ++ks) {
        bf16x8 af;
        if (XF32) {
            const float* xp = (const float*)Xv + (size_t)rowA * DD + ks * 32 + kg * 8;
            float4 f0 = *(const float4*)xp;
            float4 f1 = *(const float4*)(xp + 4);
            af[0] = (short)bf16rne(f0.x); af[1] = (short)bf16rne(f0.y);
            af[2] = (short)bf16rne(f0.z); af[3] = (short)bf16rne(f0.w);
            af[4] = (short)bf16rne(f1.x); af[5] = (short)bf16rne(f1.y);
            af[6] = (short)bf16rne(f1.z); af[7] = (short)bf16rne(f1.w);
        } else {
            const ushort_t* xp = (const ushort_t*)Xv + (size_t)rowA * DD + ks * 32 + kg * 8;
            af = *(const bf16x8*)xp;
        }
#pragma unroll
        for (int ct = 0; ct < 8; ++ct) {
            bf16x8 bf = *(const bf16x8*)&smem[(ct * 16 + m) * 136 + ks * 32 + kg * 8];
            acc[ct] = __builtin_amdgcn_mfma_f32_16x16x32_bf16(af, bf, acc[ct], 0, 0, 0);
        }
    }

    __syncthreads();   // all waves done reading W; smem becomes C-stage

    // C/D: col = ct*16 + m, row = kg*4 + rg  [m89-verified]
    ushort_t* sl = (ushort_t*)smem;          // [64 rows][132 cols]
    const int rbase = r0 + kg * 4;
    float dv[4];
#pragma unroll
    for (int rg = 0; rg < 4; ++rg) dv[rg] = dis[min(rbase + rg, NN - 1)];
#pragma unroll
    for (int ct = 0; ct < 8; ++ct) {
#pragma unroll
        for (int rg = 0; rg < 4; ++rg)
            sl[(wave * 16 + kg * 4 + rg) * 132 + ct * 16 + m] = bf16rne(acc[ct][rg] * dv[rg]);
    }

    // readback and plane-major store
    const int i = threadIdx.x >> 2;          // row within block tile 0..63
    const int q = threadIdx.x & 3;           // 8B chunk within 32B slice
    const int grow = blockIdx.x * 64 + i;
    const bool ok = grow < NN;
    const ushort_t* rb = sl + i * 132;
    uint64_t_* lp2 = (uint64_t_*)Y;
#pragma unroll
    for (int s = 0; s < 8; ++s) {
        const uint_t* p = (const uint_t*)(rb + s * 16 + q * 4);
        uint64_t_ d = (uint64_t_)p[0] | ((uint64_t_)p[1] << 32);
        uint64_t_ z = ok ? d : 0ull;
        __builtin_nontemporal_store(z, &lp2[((size_t)s * NROWS + grow) * 4 + q]);
    }
}

// ---------------- aggregation (plane-sliced, high-ILP) ----------------
// Block = 4 waves, slice s = bid&7 (-> XCD s round-robin; 3.2 MB plane L2-resident).
// Wave = 8 nodes x 8 dim-uints. Indices prefetched coalesced (4 regs = 32 edges),
// sentinel NN (zero row) for slots >= deg. 32 fully-unrolled independent gathers;
// each lane owns its (node, dim-pair) accumulator -> NO cross-lane reduction.

template<bool F32OUT>
__global__ __launch_bounds__(256) void agg_kernel(const uint_t* __restrict__ lin_planes,
                                                  const int* __restrict__ offsets,
                                                  const int* __restrict__ csr_src,
                                                  const float* __restrict__ dis,
                                                  const float* __restrict__ bias,
                                                  void* __restrict__ outv) {
    const int bid  = blockIdx.x;                // 25000 blocks
    const int s    = bid & 7;                   // slice == XCD (heuristic)
    const int gblk = bid >> 3;                  // 0..3124
    const int w    = threadIdx.x >> 6;
    const int lane = threadIdx.x & 63;
    const int g    = lane >> 3;                 // node group 0..7
    const int u    = lane & 7;                  // dim-uint within 32B slice
    const int v    = gblk * 32 + w * 8 + g;

    const int start = offsets[v];
    const int deg   = offsets[v + 1] - start;

    const uint_t* plane = lin_planes + (size_t)s * (NROWS * 8);

    // prefetch up to 32 indices: register r holds edge r*8+u of node v
    int iv[4];
    {
        const int* cp = csr_src + start + u;
        int i0 = cp[0];
        int i1 = cp[8];
        int i2 = cp[16];
        int i3 = cp[24];
        iv[0] = (u      < deg) ? i0 : NN;
        iv[1] = (u +  8 < deg) ? i1 : NN;
        iv[2] = (u + 16 < deg) ? i2 : NN;
        iv[3] = (u + 24 < deg) ? i3 : NN;
    }

    // wave max degree (over the 8 groups) to skip dead 8-edge blocks
    int wmax = deg;
    wmax = max(wmax, __shfl_xor(wmax, 8));
    wmax = max(wmax, __shfl_xor(wmax, 16));
    wmax = max(wmax, __shfl_xor(wmax, 32));

    float accx = 0.f, accy = 0.f;
    const int gbase = lane & 56;                // g*8
#pragma unroll
    for (int b = 0; b < 4; ++b) {
        if (b * 8 < wmax) {
#pragma unroll
            for (int jj = 0; jj < 8; ++jj) {
                int src = __shfl(iv[b], gbase + jj);   // edge b*8+jj of node v
                uint_t a = plane[((uint_t)src << 3) + u];
                accx += bfLo(a); accy += bfHi(a);
            }
        }
    }
    // self-loop
    {
        uint_t a = plane[((uint_t)v << 3) + u];
        accx += bfLo(a); accy += bfHi(a);
    }
    // rare deg>32 tail (group-divergent, ~1e-4 of nodes)
    if (deg > 32) {
        for (int e = start + 32; e < start + deg; ++e) {
            int src = csr_src[e];
            uint_t a = plane[((uint_t)src << 3) + u];
            accx += bfLo(a); accy += bfHi(a);
        }
    }

    const float dv = dis[v];
    const float2 b2 = ((const float2*)bias)[s * 8 + u];
    float rx = fmaxf(fmaf(dv, accx, b2.x), 0.f);
    float ry = fmaxf(fmaf(dv, accy, b2.y), 0.f);
    const size_t oidx = (size_t)v * 64 + s * 8 + u;
    if (F32OUT) {
        float2 o = make_float2(rx, ry);
        __builtin_nontemporal_store(*(const uint64_t_*)&o, (uint64_t_*)((float2*)outv + oidx));
    } else {
        uint_t pk = (uint_t)bf16rne(rx) | ((uint_t)bf16rne(ry) << 16);
        __builtin_nontemporal_store(pk, (uint_t*)outv + oidx);
    }
}

// ---------------- launch ----------------

extern "C" void kernel_launch(void* const* d_in, const int* in_sizes, int n_in,
                              void* d_out, int out_size, void* d_ws, size_t ws_size,
                              hipStream_t stream) {
    const float* x   = (const float*)d_in[0];
    const int*   ei  = (const int*)d_in[1];
    const float* Ws  = (const float*)d_in[2];
    const float* bs  = (const float*)d_in[3];

    const int* row = ei;
    const int* col = ei + NE;

    char* ws = (char*)d_ws;
    // lin planes: 8 * NROWS * 32B = 25,608,192 B (ebuf aliases low part)
    ushort_t* lin    = (ushort_t*)(ws + 0);
    int*   ebuf      = (int*)  (ws + 0);          // 6,400,000 B packed (dead before gemm)
    ushort_t* hb     = (ushort_t*)(ws + 25608192);// 25,600,000 B bf16 inter-layer h (row-major)
    float* dis       = (float*)(ws + 51208192);   // 400,000 B
    int*   offsets   = (int*)  (ws + 51608192);   // 400,004 B
    int*   csr_src   = (int*)  (ws + 52008208);   // 6,400,000 B (+overrun reads land in bukCount region: address-safe, values clamped)
    int*   bukCount  = (int*)  (ws + 58408208);   // 784 B
    int*   bukBase   = (int*)  (ws + 58409008);   // 788 B
    int*   bukCursor = (int*)  (ws + 58409808);   // 784 B
    ushort_t* wT     = (ushort_t*)(ws + 58410608);// 98,304 B

    (void)hipMemsetAsync(bukCount, 0, NBUK * sizeof(int), stream);
    f1_bucket_count<<<F1_BLOCKS, 256, 0, stream>>>(col, bukCount);
    f2_bucket_scan<<<1, 256, 0, stream>>>(bukCount, bukBase, bukCursor, offsets);
    f3_scatter<<<F3_BLOCKS, 256, 0, stream>>>(row, col, bukCursor, ebuf);
    f4_finalize<<<NBUK, 256, 0, stream>>>(ebuf, bukBase, offsets, dis, csr_src);
    wt_kernel<<<24, 256, 0, stream>>>(Ws, wT);

    const int gemmGrid = NROWS / 64;    // 1563
    const int aggGrid = (NN / 32) * 8;  // 25000
    // layer 0: f32 x -> lin planes ; agg -> bf16 hb (row-major)
    gemm_mfma<true><<<gemmGrid, 256, 0, stream>>>(x, wT, dis, lin);
    agg_kernel<false><<<aggGrid, 256, 0, stream>>>((const uint_t*)lin, offsets, csr_src, dis, bs, hb);
    // layer 1
    gemm_mfma<false><<<gemmGrid, 256, 0, stream>>>(hb, wT + 16384, dis, lin);
    agg_kernel<false><<<aggGrid, 256, 0, stream>>>((const uint_t*)lin, offsets, csr_src, dis, bs + DD, hb);
    // layer 2 -> f32 d_out
    gemm_mfma<false><<<gemmGrid, 256, 0, stream>>>(hb, wT + 32768, dis, lin);
    agg_kernel<true><<<aggGrid, 256, 0, stream>>>((const uint_t*)lin, offsets, csr_src, dis, bs + 2 * DD, d_out);
}

// Round 11
// 300.828 us; speedup vs baseline: 3.3862x; 1.0785x over previous
//
#include <hip/hip_runtime.h>
#include <hip/hip_bf16.h>

#define NN 100000
#define NROWS 100032      // NN rounded up to 64; rows >= NN are zero (gather sentinel)
#define NE 1600000
#define DD 128
#define NBUK 196          // ceil(100000 / 512) buckets of 512 target nodes
#define F1_BLOCKS 256
#define F3_BLOCKS 256
#define NGBLK 3125        // 100000 / 32 node-groups

typedef unsigned short ushort_t;
typedef unsigned int uint_t;
typedef unsigned long long uint64_t_;
typedef __attribute__((ext_vector_type(8))) short bf16x8;
typedef __attribute__((ext_vector_type(4))) float f32x4;

__device__ __forceinline__ ushort_t bf16rne(float f) {
    uint_t u = __float_as_uint(f);
    u += 0x7FFF + ((u >> 16) & 1);
    return (ushort_t)(u >> 16);
}
__device__ __forceinline__ float bfLo(uint_t u) { return __uint_as_float(u << 16); }
__device__ __forceinline__ float bfHi(uint_t u) { return __uint_as_float(u & 0xFFFF0000u); }

// ---------------- CSR build (bucketed counting sort) ----------------

__global__ __launch_bounds__(256) void f1_bucket_count(const int* __restrict__ col,
                                                       int* __restrict__ bukCount) {
    __shared__ int hist[NBUK];
    for (int t = threadIdx.x; t < NBUK; t += 256) hist[t] = 0;
    __syncthreads();
    const int epb = (NE + F1_BLOCKS - 1) / F1_BLOCKS;
    const int e0 = blockIdx.x * epb;
    const int e1 = min(e0 + epb, NE);
    for (int e = e0 + threadIdx.x; e < e1; e += 256)
        atomicAdd(&hist[col[e] >> 9], 1);
    __syncthreads();
    for (int t = threadIdx.x; t < NBUK; t += 256)
        if (hist[t]) atomicAdd(&bukCount[t], hist[t]);
}

__global__ void f2_bucket_scan(const int* __restrict__ bukCount,
                               int* __restrict__ bukBase,
                               int* __restrict__ bukCursor,
                               int* __restrict__ offsets) {
    __shared__ int s[256];
    const int t = threadIdx.x;
    int v = (t < NBUK) ? bukCount[t] : 0;
    s[t] = v;
    __syncthreads();
    for (int off = 1; off < 256; off <<= 1) {
        int tmp = (t >= off) ? s[t - off] : 0;
        __syncthreads();
        s[t] += tmp;
        __syncthreads();
    }
    int excl = s[t] - v;
    if (t < NBUK) { bukBase[t] = excl; bukCursor[t] = excl; }
    if (t == 255) { bukBase[NBUK] = s[255]; offsets[NN] = s[255]; }
}

// per-wave LDS histograms; ebuf packed as (row<<9)|col_local
__global__ __launch_bounds__(256) void f3_scatter(const int* __restrict__ row,
                                                  const int* __restrict__ col,
                                                  int* __restrict__ bukCursor,
                                                  int* __restrict__ ebuf) {
    __shared__ int hist[4][NBUK];
    __shared__ int base[4][NBUK];
    const int t = threadIdx.x;
    const int w = t >> 6;
    const int lane = t & 63;
    for (int i = t; i < 4 * NBUK; i += 256) (&hist[0][0])[i] = 0;
    __syncthreads();
    const int epb = (NE + F3_BLOCKS - 1) / F3_BLOCKS;
    const int e0 = blockIdx.x * epb;
    const int e1 = min(e0 + epb, NE);
    const int wepb = (e1 - e0 + 3) >> 2;
    const int we0 = e0 + w * wepb;
    const int we1 = min(we0 + wepb, e1);
    for (int e = we0 + lane; e < we1; e += 64)
        atomicAdd(&hist[w][col[e] >> 9], 1);
    __syncthreads();
    if (t < NBUK) {
        int h0 = hist[0][t], h1 = hist[1][t], h2 = hist[2][t], h3 = hist[3][t];
        int tot = h0 + h1 + h2 + h3;
        int g = tot ? atomicAdd(&bukCursor[t], tot) : 0;
        base[0][t] = g; base[1][t] = g + h0;
        base[2][t] = g + h0 + h1; base[3][t] = g + h0 + h1 + h2;
        hist[0][t] = 0; hist[1][t] = 0; hist[2][t] = 0; hist[3][t] = 0;
    }
    __syncthreads();
    for (int e = we0 + lane; e < we1; e += 64) {
        int c = col[e];
        int b = c >> 9;
        int r = atomicAdd(&hist[w][b], 1);
        ebuf[base[w][b] + r] = (row[e] << 9) | (c & 511);
    }
}

__global__ __launch_bounds__(256) void f4_finalize(const int* __restrict__ ebuf,
                                                   const int* __restrict__ bukBase,
                                                   int* __restrict__ offsets,
                                                   float* __restrict__ dis,
                                                   int* __restrict__ csr_src) {
    __shared__ int cnt[512];
    __shared__ int cur[512];
    __shared__ int s[256];
    const int t = threadIdx.x;
    const int colBase = blockIdx.x << 9;
    const int ncols = min(512, NN - colBase);
    cnt[t] = 0; cnt[t + 256] = 0;
    __syncthreads();
    const int eb0 = bukBase[blockIdx.x];
    const int eb1 = bukBase[blockIdx.x + 1];
    for (int e = eb0 + t; e < eb1; e += 256)
        atomicAdd(&cnt[ebuf[e] & 511], 1);
    __syncthreads();
    const int c0 = cnt[2 * t], c1 = cnt[2 * t + 1];
    const int psum = c0 + c1;
    s[t] = psum;
    __syncthreads();
    for (int off = 1; off < 256; off <<= 1) {
        int tmp = (t >= off) ? s[t - off] : 0;
        __syncthreads();
        s[t] += tmp;
        __syncthreads();
    }
    const int exclPair = s[t] - psum;
    const int g0 = eb0 + exclPair;
    const int g1 = g0 + c0;
    cur[2 * t] = g0; cur[2 * t + 1] = g1;
    if (2 * t < ncols)     { offsets[colBase + 2 * t]     = g0; dis[colBase + 2 * t]     = rsqrtf((float)(c0 + 1)); }
    if (2 * t + 1 < ncols) { offsets[colBase + 2 * t + 1] = g1; dis[colBase + 2 * t + 1] = rsqrtf((float)(c1 + 1)); }
    __syncthreads();
    for (int e = eb0 + t; e < eb1; e += 256) {
        int pc = ebuf[e];
        int p = atomicAdd(&cur[pc & 511], 1);
        csr_src[p] = pc >> 9;
    }
}

// ---------------- W prep: bf16 + transpose wT[l][col][k] ----------------

__global__ __launch_bounds__(256) void wt_kernel(const float* __restrict__ Ws,
                                                 ushort_t* __restrict__ wT) {
    int idx = blockIdx.x * 256 + threadIdx.x;
    if (idx >= 3 * 128 * 16) return;
    int l = idx >> 11;
    int r = idx & 2047;
    int c = r >> 4;
    int kc = r & 15;
    const float* w = Ws + l * 16384;
    ushort_t tmp[8];
#pragma unroll
    for (int e = 0; e < 8; ++e)
        tmp[e] = bf16rne(w[(kc * 8 + e) * 128 + c]);
    *(uint4*)&wT[(size_t)l * 16384 + c * 128 + kc * 8] = *(uint4*)tmp;
}

// ---------------- MFMA GEMM -> 4-slice-major Y ----------------
// Y layout: 4 slices, slice s = [NROWS][64B] = dims [s*32, s*32+32) of each row.
// Rows >= NN written as zero in every slice (gather sentinels).

template<bool XF32>
__global__ __launch_bounds__(256) void gemm_mfma(const void* __restrict__ Xv,
                                                 const ushort_t* __restrict__ wT,
                                                 const float* __restrict__ dis,
                                                 ushort_t* __restrict__ Y) {
    __shared__ short smem[128 * 136];   // 34.8 KB: W-stage, then bf16-C stage
    {
        const uint4* src = (const uint4*)wT;
        int t = threadIdx.x;
#pragma unroll
        for (int i = 0; i < 8; ++i) {
            int idx = i * 256 + t;
            int rowc = idx >> 4;
            int kc = idx & 15;
            uint4 v = src[idx];
            *(uint4*)&smem[rowc * 136 + kc * 8] = v;
        }
    }
    __syncthreads();

    const int wave = threadIdx.x >> 6;
    const int lane = threadIdx.x & 63;
    const int m = lane & 15;
    const int kg = lane >> 4;
    const int r0 = blockIdx.x * 64 + wave * 16;
    const int rowA = min(r0 + m, NN - 1);

    f32x4 acc[8];
#pragma unroll
    for (int ct = 0; ct < 8; ++ct) acc[ct] = (f32x4){0.f, 0.f, 0.f, 0.f};

#pragma unroll
    for (int ks = 0; ks < 4; ++ks) {
        bf16x8 af;
        if (XF32) {
            const float* xp = (const float*)Xv + (size_t)rowA * DD + ks * 32 + kg * 8;
            float4 f0 = *(const float4*)xp;
            float4 f1 = *(const float4*)(xp + 4);
            af[0] = (short)bf16rne(f0.x); af[1] = (short)bf16rne(f0.y);
            af[2] = (short)bf16rne(f0.z); af[3] = (short)bf16rne(f0.w);
            af[4] = (short)bf16rne(f1.x); af[5] = (short)bf16rne(f1.y);
            af[6] = (short)bf16rne(f1.z); af[7] = (short)bf16rne(f1.w);
        } else {
            const ushort_t* xp = (const ushort_t*)Xv + (size_t)rowA * DD + ks * 32 + kg * 8;
            af = *(const bf16x8*)xp;
        }
#pragma unroll
        for (int ct = 0; ct < 8; ++ct) {
            bf16x8 bf = *(const bf16x8*)&smem[(ct * 16 + m) * 136 + ks * 32 + kg * 8];
            acc[ct] = __builtin_amdgcn_mfma_f32_16x16x32_bf16(af, bf, acc[ct], 0, 0, 0);
        }
    }

    __syncthreads();   // all waves done reading W; smem becomes C-stage

    // C/D: col = ct*16 + m, row = kg*4 + rg  [m89-verified]
    ushort_t* sl = (ushort_t*)smem;          // [64 rows][132 cols]
    const int rbase = r0 + kg * 4;
    float dv[4];
#pragma unroll
    for (int rg = 0; rg < 4; ++rg) dv[rg] = dis[min(rbase + rg, NN - 1)];
#pragma unroll
    for (int ct = 0; ct < 8; ++ct) {
#pragma unroll
        for (int rg = 0; rg < 4; ++rg)
            sl[(wave * 16 + kg * 4 + rg) * 132 + ct * 16 + m] = bf16rne(acc[ct][rg] * dv[rg]);
    }

    // readback and 4-slice-major store (16B per lane per slice)
    const int i = threadIdx.x >> 2;          // row within block tile 0..63
    const int q = threadIdx.x & 3;           // 16B chunk within 64B slice
    const int grow = blockIdx.x * 64 + i;
    const bool ok = grow < NN;
    const ushort_t* rb = sl + i * 132;
#pragma unroll
    for (int s = 0; s < 4; ++s) {
        const uint_t* p = (const uint_t*)(rb + s * 32 + q * 8);
        uint64_t_ d0 = (uint64_t_)p[0] | ((uint64_t_)p[1] << 32);
        uint64_t_ d1 = (uint64_t_)p[2] | ((uint64_t_)p[3] << 32);
        if (!ok) { d0 = 0ull; d1 = 0ull; }
        uint64_t_* dst = (uint64_t_*)((char*)Y + ((size_t)s * NROWS + grow) * 64 + q * 16);
        __builtin_nontemporal_store(d0, dst);
        __builtin_nontemporal_store(d1, dst + 1);
    }
}

// ---------------- aggregation (4-slice, 64B-line gathers) ----------------
// Slice = 64B (32 dims). xcd = bid&7; slice = xcd>>1 (2 XCDs per 6.4MB slice).
// Wave = 8 nodes x 8 lanes x 8B -> every gather instruction = 8 full 64B lines.
// Indices prefetched coalesced (4 regs = 32 edges/node); sentinel row NN is zero.

template<bool F32OUT>
__global__ __launch_bounds__(256) void agg_kernel(const uint_t* __restrict__ lin_sl,
                                                  const int* __restrict__ offsets,
                                                  const int* __restrict__ csr_src,
                                                  const float* __restrict__ dis,
                                                  const float* __restrict__ bias,
                                                  void* __restrict__ outv) {
    const int bid  = blockIdx.x;                // 12504 blocks
    const int xcd  = bid & 7;
    const int sli  = xcd >> 1;                  // slice 0..3
    const int gblk = (bid >> 3) * 2 + (xcd & 1);
    if (gblk >= NGBLK) return;
    const int w    = threadIdx.x >> 6;
    const int lane = threadIdx.x & 63;
    const int g    = lane >> 3;                 // node group 0..7
    const int u    = lane & 7;                  // uint2 (8B) within 64B slice
    const int v    = gblk * 32 + w * 8 + g;

    const int start = offsets[v];
    const int deg   = offsets[v + 1] - start;

    const uint_t* plane = lin_sl + (size_t)sli * (NROWS * 16);   // 16 uints per row

    // prefetch up to 32 indices: register r holds edge r*8+u of node v
    int iv[4];
    {
        const int* cp = csr_src + start + u;
        int i0 = cp[0];
        int i1 = cp[8];
        int i2 = cp[16];
        int i3 = cp[24];
        iv[0] = (u      < deg) ? i0 : NN;
        iv[1] = (u +  8 < deg) ? i1 : NN;
        iv[2] = (u + 16 < deg) ? i2 : NN;
        iv[3] = (u + 24 < deg) ? i3 : NN;
    }

    // wave max degree (over the 8 groups) to skip dead 8-edge blocks
    int wmax = deg;
    wmax = max(wmax, __shfl_xor(wmax, 8));
    wmax = max(wmax, __shfl_xor(wmax, 16));
    wmax = max(wmax, __shfl_xor(wmax, 32));

    float a0 = 0.f, a1 = 0.f, a2 = 0.f, a3 = 0.f;
    const int gbase = lane & 56;                // g*8
#pragma unroll
    for (int b = 0; b < 4; ++b) {
        if (b * 8 < wmax) {
#pragma unroll
            for (int jj = 0; jj < 8; ++jj) {
                int src = __shfl(iv[b], gbase + jj);   // edge b*8+jj of node v
                uint2 a = *(const uint2*)(plane + ((size_t)src << 4) + u * 2);
                a0 += bfLo(a.x); a1 += bfHi(a.x);
                a2 += bfLo(a.y); a3 += bfHi(a.y);
            }
        }
    }
    // self-loop
    {
        uint2 a = *(const uint2*)(plane + ((size_t)v << 4) + u * 2);
        a0 += bfLo(a.x); a1 += bfHi(a.x);
        a2 += bfLo(a.y); a3 += bfHi(a.y);
    }
    // rare deg>32 tail (group-divergent)
    if (deg > 32) {
        for (int e = start + 32; e < start + deg; ++e) {
            int src = csr_src[e];
            uint2 a = *(const uint2*)(plane + ((size_t)src << 4) + u * 2);
            a0 += bfLo(a.x); a1 += bfHi(a.x);
            a2 += bfLo(a.y); a3 += bfHi(a.y);
        }
    }

    const float dv = dis[v];
    const float4 b4 = ((const float4*)bias)[sli * 8 + u];
    float r0 = fmaxf(fmaf(dv, a0, b4.x), 0.f);
    float r1 = fmaxf(fmaf(dv, a1, b4.y), 0.f);
    float r2 = fmaxf(fmaf(dv, a2, b4.z), 0.f);
    float r3 = fmaxf(fmaf(dv, a3, b4.w), 0.f);
    if (F32OUT) {
        float* op = (float*)outv + (size_t)v * DD + sli * 32 + u * 4;
        float2 lo = make_float2(r0, r1);
        float2 hi = make_float2(r2, r3);
        __builtin_nontemporal_store(*(const uint64_t_*)&lo, (uint64_t_*)op);
        __builtin_nontemporal_store(*(const uint64_t_*)&hi, (uint64_t_*)op + 1);
    } else {
        uint_t p0 = (uint_t)bf16rne(r0) | ((uint_t)bf16rne(r1) << 16);
        uint_t p1 = (uint_t)bf16rne(r2) | ((uint_t)bf16rne(r3) << 16);
        uint64_t_ pk = (uint64_t_)p0 | ((uint64_t_)p1 << 32);
        __builtin_nontemporal_store(pk, (uint64_t_*)((uint_t*)outv + (size_t)v * 64 + sli * 16 + u * 2));
    }
}

// ---------------- launch ----------------

extern "C" void kernel_launch(void* const* d_in, const int* in_sizes, int n_in,
                              void* d_out, int out_size, void* d_ws, size_t ws_size,
                              hipStream_t stream) {
    const float* x   = (const float*)d_in[0];
    const int*   ei  = (const int*)d_in[1];
    const float* Ws  = (const float*)d_in[2];
    const float* bs  = (const float*)d_in[3];

    const int* row = ei;
    const int* col = ei + NE;

    char* ws = (char*)d_ws;
    // lin slices: 4 * NROWS * 64B = 25,608,192 B (ebuf aliases low part)
    ushort_t* lin    = (ushort_t*)(ws + 0);
    int*   ebuf      = (int*)  (ws + 0);          // 6,400,000 B packed (dead before gemm)
    ushort_t* hb     = (ushort_t*)(ws + 25608192);// 25,600,000 B bf16 inter-layer h (row-major)
    float* dis       = (float*)(ws + 51208192);   // 400,000 B
    int*   offsets   = (int*)  (ws + 51608192);   // 400,004 B
    int*   csr_src   = (int*)  (ws + 52008208);   // 6,400,000 B (+127B overrun reads land in bukCount region: address-safe, values clamped)
    int*   bukCount  = (int*)  (ws + 58408208);   // 784 B
    int*   bukBase   = (int*)  (ws + 58409008);   // 788 B
    int*   bukCursor = (int*)  (ws + 58409808);   // 784 B
    ushort_t* wT     = (ushort_t*)(ws + 58410608);// 98,304 B

    (void)hipMemsetAsync(bukCount, 0, NBUK * sizeof(int), stream);
    f1_bucket_count<<<F1_BLOCKS, 256, 0, stream>>>(col, bukCount);
    f2_bucket_scan<<<1, 256, 0, stream>>>(bukCount, bukBase, bukCursor, offsets);
    f3_scatter<<<F3_BLOCKS, 256, 0, stream>>>(row, col, bukCursor, ebuf);
    f4_finalize<<<NBUK, 256, 0, stream>>>(ebuf, bukBase, offsets, dis, csr_src);
    wt_kernel<<<24, 256, 0, stream>>>(Ws, wT);

    const int gemmGrid = NROWS / 64;                 // 1563
    const int aggGrid = ((NGBLK + 1) / 2) * 8;       // 12504
    // layer 0: f32 x -> lin slices ; agg -> bf16 hb (row-major)
    gemm_mfma<true><<<gemmGrid, 256, 0, stream>>>(x, wT, dis, lin);
    agg_kernel<false><<<aggGrid, 256, 0, stream>>>((const uint_t*)lin, offsets, csr_src, dis, bs, hb);
    // layer 1
    gemm_mfma<false><<<gemmGrid, 256, 0, stream>>>(hb, wT + 16384, dis, lin);
    agg_kernel<false><<<aggGrid, 256, 0, stream>>>((const uint_t*)lin, offsets, csr_src, dis, bs + DD, hb);
    // layer 2 -> f32 d_out
    gemm_mfma<false><<<gemmGrid, 256, 0, stream>>>(hb, wT + 32768, dis, lin);
    agg_kernel<true><<<aggGrid, 256, 0, stream>>>((const uint_t*)lin, offsets, csr_src, dis, bs + 2 * DD, d_out);
}